// Round 1
// baseline (2995.455 us; speedup 1.0000x reference)
//
#include <hip/hip_runtime.h>

typedef unsigned short u16;
typedef unsigned int u32;
typedef __attribute__((ext_vector_type(4))) float f32x4;
typedef __attribute__((ext_vector_type(8))) __bf16 bf16x8;

__device__ __forceinline__ u16 f2bf(float f) {
  u32 u = __builtin_bit_cast(u32, f);
  u += 0x7FFFu + ((u >> 16) & 1u);
  return (u16)(u >> 16);
}
__device__ __forceinline__ float bf2f(u16 h) {
  return __builtin_bit_cast(float, (u32)h << 16);
}

// ---------------------------------------------------------------------------
// Generic split: fp32 -> bf16 hi + bf16 lo (residual)
// ---------------------------------------------------------------------------
__global__ __launch_bounds__(256) void k_split(const float* __restrict__ in,
                                               u16* __restrict__ hi, u16* __restrict__ lo, int n) {
  int i = blockIdx.x * 256 + threadIdx.x;
  if (i >= n) return;
  float v = in[i];
  u16 h = f2bf(v);
  hi[i] = h;
  lo[i] = f2bf(v - bf2f(h));
}

// ---------------------------------------------------------------------------
// Transpose + convert (+ optional unit-major gate permute on out-rows):
// in: W fp32 [K][N] row-major  ->  out: bf16 [N][K] (B^T layout for gemm_bt)
// PERM: out row n' pulls input col (n'&3)*512 + (n'>>2)   (i,f,g,o -> unit-major)
// ---------------------------------------------------------------------------
template<bool PERM, bool SPLIT>
__global__ __launch_bounds__(256) void k_transconv(const float* __restrict__ W,
                                                   u16* __restrict__ Thi, u16* __restrict__ Tlo,
                                                   int K, int N) {
  __shared__ float tile[32][33];
  int n0 = blockIdx.x * 32, k0 = blockIdx.y * 32;
  int tx = threadIdx.x & 31, ty = threadIdx.x >> 5;
#pragma unroll
  for (int i = 0; i < 4; ++i) {
    int kk = ty + i * 8;
    int np = n0 + tx;
    int nin = PERM ? ((np & 3) * 512 + (np >> 2)) : np;
    tile[kk][tx] = W[(size_t)(k0 + kk) * N + nin];
  }
  __syncthreads();
#pragma unroll
  for (int i = 0; i < 4; ++i) {
    int rr = ty + i * 8;
    float v = tile[tx][rr];
    u16 h = f2bf(v);
    Thi[(size_t)(n0 + rr) * K + k0 + tx] = h;
    if (SPLIT) Tlo[(size_t)(n0 + rr) * K + k0 + tx] = f2bf(v - bf2f(h));
  }
}

// ---------------------------------------------------------------------------
// hw2[b][u] = estado_h[b]·W2[:,u] + b1[u] + b2[u]    (fp32, 32 blocks)
// ---------------------------------------------------------------------------
__global__ __launch_bounds__(256) void k_hw2(const float* __restrict__ h0, const float* __restrict__ W2,
                                             const float* __restrict__ b1, const float* __restrict__ b2,
                                             float* __restrict__ hw2) {
  int b = blockIdx.x;
  __shared__ float hs[512];
  for (int i = threadIdx.x; i < 512; i += 256) hs[i] = h0[b * 512 + i];
  __syncthreads();
  for (int u = threadIdx.x; u < 512; u += 256) {
    float acc = 0.f;
#pragma unroll 4
    for (int k = 0; k < 512; ++k) acc = fmaf(hs[k], W2[k * 512 + u], acc);
    hw2[b * 512 + u] = acc + b1[u] + b2[u];
  }
}

// ---------------------------------------------------------------------------
// score[r] = t1[r,:]·Va + bV   (t1 already tanh'ed), one wave per row
// ---------------------------------------------------------------------------
__global__ __launch_bounds__(256) void k_score(const float* __restrict__ t1, const float* __restrict__ Va,
                                               const float* __restrict__ bV, float* __restrict__ score) {
  int r = blockIdx.x * 4 + (threadIdx.x >> 6);
  int l = threadIdx.x & 63;
  const float* row = t1 + (size_t)r * 512;
  float acc = 0.f;
#pragma unroll
  for (int i = 0; i < 8; ++i) acc = fmaf(row[l + 64 * i], Va[l + 64 * i], acc);
#pragma unroll
  for (int off = 32; off >= 1; off >>= 1) acc += __shfl_down(acc, off, 64);
  if (l == 0) score[r] = acc + bV[0];
}

// ---------------------------------------------------------------------------
// softmax over S=128 + ctx[b] = sum_s pesos*enc ; writes pesos to d_out
// ---------------------------------------------------------------------------
__global__ __launch_bounds__(128) void k_softmax_ctx(const float* __restrict__ score,
                                                     const float* __restrict__ enc,
                                                     float* __restrict__ pesos, float* __restrict__ ctx) {
  int b = blockIdx.x, s = threadIdx.x;
  __shared__ float red[128], ps[128];
  float sc = score[(b << 7) + s];
  red[s] = sc;
  __syncthreads();
  for (int off = 64; off >= 1; off >>= 1) {
    if (s < off) red[s] = fmaxf(red[s], red[s + off]);
    __syncthreads();
  }
  float mx = red[0];
  __syncthreads();
  float e = expf(sc - mx);
  red[s] = e;
  __syncthreads();
  for (int off = 64; off >= 1; off >>= 1) {
    if (s < off) red[s] += red[s + off];
    __syncthreads();
  }
  float p = e / red[0];
  pesos[(b << 7) + s] = p;
  ps[s] = p;
  __syncthreads();
  for (int e0 = s; e0 < 512; e0 += 128) {
    float acc = 0.f;
    for (int si = 0; si < 128; ++si)
      acc = fmaf(ps[si], enc[((size_t)(b << 7) + si) * 512 + e0], acc);
    ctx[(b << 9) + e0] = acc;
  }
}

// ---------------------------------------------------------------------------
// xcat[row=t*32+b][0:256]=emb[x[b,t]], [256:768]=ctx[b]  -> bf16 hi/lo splits
// ---------------------------------------------------------------------------
__global__ __launch_bounds__(256) void k_embcat(const int* __restrict__ x, const float* __restrict__ emb,
                                                const float* __restrict__ ctx,
                                                u16* __restrict__ xhi, u16* __restrict__ xlo) {
  int r = blockIdx.x;
  int t = r >> 5, b = r & 31;
  int tok = x[b * 64 + t];
  for (int c = threadIdx.x; c < 768; c += 256) {
    float v = (c < 256) ? emb[(size_t)tok * 256 + c] : ctx[(b << 9) + (c - 256)];
    u16 h = f2bf(v);
    xhi[(size_t)r * 768 + c] = h;
    xlo[(size_t)r * 768 + c] = f2bf(v - bf2f(h));
  }
}

// bias permute: blp[c'] = bl[(c'&3)*512 + (c'>>2)]
__global__ __launch_bounds__(256) void k_permbias(const float* __restrict__ bl, float* __restrict__ blp) {
  int i = blockIdx.x * 256 + threadIdx.x;
  if (i < 2048) blp[i] = bl[(i & 3) * 512 + (i >> 2)];
}

// init: hstate rows 0 <- split(estado_h); c_buf <- estado_c
__global__ __launch_bounds__(256) void k_initstate(const float* __restrict__ h0, const float* __restrict__ c0,
                                                   u16* __restrict__ hhi, u16* __restrict__ hlo,
                                                   float* __restrict__ cbuf) {
  int i = blockIdx.x * 256 + threadIdx.x;  // 16384
  float v = h0[i];
  u16 h = f2bf(v);
  hhi[i] = h;
  hlo[i] = f2bf(v - bf2f(h));
  cbuf[i] = c0[i];
}

// ---------------------------------------------------------------------------
// MFMA GEMM, C[M,N] = A[M,K] @ B[K,N], B passed TRANSPOSED bf16 [N][K].
// A passed as bf16 splits (hi,lo). NPASS=2: Ahi*Bhi+Alo*Bhi ; NPASS=3: +Ahi*Blo.
// 128x128 tile, BK=32, 256 threads (4 waves, 2x2 of 64x64).
// EPI 0: C = tanh(acc + aux[(row>>7)*N + col])      (attention t1)
// EPI 1: C = acc + aux[col]                          (xpre + bias)
// EPI 2: C[(b*64+t)*N+col] = acc + aux[col], b=row&31,t=row>>5   (projection)
// LDS 16B-chunk xor swizzle (cc ^ ((row>>1)&3)) => 2-way (free) bank aliasing.
// ---------------------------------------------------------------------------
template<int NPASS, int EPI>
__global__ __launch_bounds__(256) void gemm_bt(const u16* __restrict__ Ahi, const u16* __restrict__ Alo,
                                               const u16* __restrict__ Bhi, const u16* __restrict__ Blo,
                                               float* __restrict__ C, const float* __restrict__ aux,
                                               int M, int N, int K) {
  __shared__ u16 sAhi[128][32], sAlo[128][32], sBhi[128][32], sBlo[128][32];
  const int NT = N >> 7;
  const int bm = blockIdx.x / NT, bn = blockIdx.x % NT;
  const int rowA0 = bm << 7, rowB0 = bn << 7;
  const int tid = threadIdx.x;
  const int l = tid & 63;
  const int w = tid >> 6, wr = w >> 1, wc = w & 1;
  const int lr = l & 15, kc = l >> 4;
  const int swz = (kc ^ ((lr >> 1) & 3)) << 3;
  f32x4 acc[4][4] = {};
  for (int ks = 0; ks < K; ks += 32) {
#pragma unroll
    for (int c = 0; c < 2; ++c) {
      int q = tid + (c << 8);
      int row = q >> 2, cc = q & 3;
      int slot = (cc ^ ((row >> 1) & 3)) << 3;
      size_t ga = (size_t)(rowA0 + row) * K + ks + (cc << 3);
      size_t gb = (size_t)(rowB0 + row) * K + ks + (cc << 3);
      *(uint4*)&sAhi[row][slot] = *(const uint4*)(Ahi + ga);
      *(uint4*)&sAlo[row][slot] = *(const uint4*)(Alo + ga);
      *(uint4*)&sBhi[row][slot] = *(const uint4*)(Bhi + gb);
      if (NPASS == 3) *(uint4*)&sBlo[row][slot] = *(const uint4*)(Blo + gb);
    }
    __syncthreads();
    bf16x8 ah[4], al[4], bh[4], bl2[4];
#pragma unroll
    for (int m = 0; m < 4; ++m) {
      ah[m] = *(const bf16x8*)&sAhi[(wr << 6) + (m << 4) + lr][swz];
      al[m] = *(const bf16x8*)&sAlo[(wr << 6) + (m << 4) + lr][swz];
      bh[m] = *(const bf16x8*)&sBhi[(wc << 6) + (m << 4) + lr][swz];
      if (NPASS == 3) bl2[m] = *(const bf16x8*)&sBlo[(wc << 6) + (m << 4) + lr][swz];
    }
#pragma unroll
    for (int m = 0; m < 4; ++m)
#pragma unroll
      for (int n = 0; n < 4; ++n) {
        acc[m][n] = __builtin_amdgcn_mfma_f32_16x16x32_bf16(ah[m], bh[n], acc[m][n], 0, 0, 0);
        acc[m][n] = __builtin_amdgcn_mfma_f32_16x16x32_bf16(al[m], bh[n], acc[m][n], 0, 0, 0);
        if (NPASS == 3)
          acc[m][n] = __builtin_amdgcn_mfma_f32_16x16x32_bf16(ah[m], bl2[n], acc[m][n], 0, 0, 0);
      }
    __syncthreads();
  }
#pragma unroll
  for (int m = 0; m < 4; ++m)
#pragma unroll
    for (int n = 0; n < 4; ++n)
#pragma unroll
      for (int r = 0; r < 4; ++r) {
        int rr = rowA0 + (wr << 6) + (m << 4) + (kc << 2) + r;
        int col = rowB0 + (wc << 6) + (n << 4) + lr;
        float v = acc[m][n][r];
        if (EPI == 0) {
          C[(size_t)rr * N + col] = tanhf(v + aux[(rr >> 7) * N + col]);
        } else if (EPI == 1) {
          C[(size_t)rr * N + col] = v + aux[col];
        } else {
          int b = rr & 31, t = rr >> 5;
          C[(size_t)(b * 64 + t) * N + col] = v + aux[col];
        }
      }
}

// ---------------------------------------------------------------------------
// LSTM scan (one layer, T steps). Cooperative: 64 blocks x 128 threads.
// Block j owns 32 permuted z-columns (units 8j..8j+8, gates i,f,g,o).
// Wh^T (bf16, unit-major permuted) tile preloaded into VGPRs (time-invariant).
// h state kept as bf16 hi/lo splits in global hstate[(T+1)*32][512];
// z = h@Wh via 2-pass split MFMA; xpre (x@Wx + bias) precomputed fp32.
// Grid barrier: monotone counter, agent-scope acq/rel atomics.
// ---------------------------------------------------------------------------
struct ScanArgs {
  const float* xpre;   // [T*32][2048] fp32, unit-major cols, includes bias
  const u16* Wht;      // [2048][512] bf16 (B^T, permuted)
  u16* hhi;            // [(T+1)*32][512]
  u16* hlo;
  float* cbuf;         // [32][512] fp32
  float* hT_out;       // d_out slices (layer 2) or nullptr
  float* cT_out;
  u32* cnt;            // barrier counter (zeroed per launch)
  int T;
  int write_hc;
};

__device__ __forceinline__ void gridbar(u32* cnt, u32 target) {
  __syncthreads();
  if (threadIdx.x == 0) {
    __hip_atomic_fetch_add(cnt, 1u, __ATOMIC_ACQ_REL, __HIP_MEMORY_SCOPE_AGENT);
    while (__hip_atomic_load(cnt, __ATOMIC_ACQUIRE, __HIP_MEMORY_SCOPE_AGENT) < target)
      __builtin_amdgcn_s_sleep(2);
  }
  __syncthreads();
}

__global__ __launch_bounds__(128) void lstm_scan(ScanArgs a) {
  const int j = blockIdx.x;
  const int tid = threadIdx.x;
  const int l = tid & 63, w = tid >> 6;
  const int lr = l & 15, kc = l >> 4;
  __shared__ float zs[32][33];
  bf16x8 breg[16];
  {
    const u16* bp = a.Wht + (size_t)(32 * j + 16 * w + lr) * 512 + (kc << 3);
#pragma unroll
    for (int q = 0; q < 16; ++q) breg[q] = *(const bf16x8*)(bp + (q << 5));
  }
  for (int t = 0; t < a.T; ++t) {
    f32x4 acc0 = {0.f, 0.f, 0.f, 0.f}, acc1 = {0.f, 0.f, 0.f, 0.f};
    const u16* hh = a.hhi + ((size_t)t << 14) + ((size_t)lr << 9) + (kc << 3);
    const u16* hl = a.hlo + ((size_t)t << 14) + ((size_t)lr << 9) + (kc << 3);
#pragma unroll
    for (int q = 0; q < 16; ++q) {
      bf16x8 a0 = *(const bf16x8*)(hh + (q << 5));
      bf16x8 a1 = *(const bf16x8*)(hh + 8192 + (q << 5));
      bf16x8 c0 = *(const bf16x8*)(hl + (q << 5));
      bf16x8 c1 = *(const bf16x8*)(hl + 8192 + (q << 5));
      acc0 = __builtin_amdgcn_mfma_f32_16x16x32_bf16(a0, breg[q], acc0, 0, 0, 0);
      acc1 = __builtin_amdgcn_mfma_f32_16x16x32_bf16(a1, breg[q], acc1, 0, 0, 0);
      acc0 = __builtin_amdgcn_mfma_f32_16x16x32_bf16(c0, breg[q], acc0, 0, 0, 0);
      acc1 = __builtin_amdgcn_mfma_f32_16x16x32_bf16(c1, breg[q], acc1, 0, 0, 0);
    }
#pragma unroll
    for (int r = 0; r < 4; ++r) {
      zs[(kc << 2) + r][(w << 4) + lr] = acc0[r];
      zs[16 + (kc << 2) + r][(w << 4) + lr] = acc1[r];
    }
    __syncthreads();
#pragma unroll
    for (int pp = 0; pp < 2; ++pp) {
      int p = tid + (pp << 7);
      int ul = p >> 5, b = p & 31;
      float4 zx = *(const float4*)(a.xpre + (size_t)((t << 5) + b) * 2048 + (j << 5) + (ul << 2));
      float zi = zs[b][(ul << 2) + 0] + zx.x;
      float zf = zs[b][(ul << 2) + 1] + zx.y;
      float zg = zs[b][(ul << 2) + 2] + zx.z;
      float zo = zs[b][(ul << 2) + 3] + zx.w;
      int ug = (j << 3) + ul;
      float co = a.cbuf[(b << 9) + ug];
      float si = 1.f / (1.f + expf(-zi));
      float sf = 1.f / (1.f + expf(-zf));
      float so = 1.f / (1.f + expf(-zo));
      float cn = sf * co + si * tanhf(zg);
      float hn = so * tanhf(cn);
      a.cbuf[(b << 9) + ug] = cn;
      u16 hb = f2bf(hn);
      size_t ho = ((size_t)(t + 1) << 14) + (b << 9) + ug;
      a.hhi[ho] = hb;
      a.hlo[ho] = f2bf(hn - bf2f(hb));
      if (a.write_hc && t == a.T - 1) {
        a.hT_out[(b << 9) + ug] = hn;
        a.cT_out[(b << 9) + ug] = cn;
      }
    }
    if (t != a.T - 1) gridbar(a.cnt, (u32)(64 * (t + 1)));
  }
}

// ---------------------------------------------------------------------------
// Workspace layout (bytes). Region [0, 34.6MB) is reused for Wfc^T bf16 after
// attention + xpre GEMMs are done. Total requirement ~64.4 MB.
// ---------------------------------------------------------------------------
static constexpr size_t OFF_ENC_HI = 0;
static constexpr size_t OFF_ENC_LO = 4194304;
static constexpr size_t OFF_W1T_HI = 8388608;
static constexpr size_t OFF_W1T_LO = 8912896;
static constexpr size_t OFF_XCAT_HI = 9437184;
static constexpr size_t OFF_XCAT_LO = 12582912;
static constexpr size_t OFF_WX1T_HI = 15728640;
static constexpr size_t OFF_WX1T_LO = 18874368;
static constexpr size_t OFF_WX2T_HI = 22020096;
static constexpr size_t OFF_WX2T_LO = 24117248;
static constexpr size_t OFF_T1 = 26214400;       // 8.39MB, ends 34,603,008
static constexpr size_t OFF_WFCT = 0;            // 32.77MB alias, after deps dead
static constexpr size_t OFF_HW2 = 34603008;
static constexpr size_t OFF_SCORE = 34668544;
static constexpr size_t OFF_CTX = 34684928;
static constexpr size_t OFF_BL1P = 34750464;
static constexpr size_t OFF_BL2P = 34758656;
static constexpr size_t OFF_WH1T = 34766848;
static constexpr size_t OFF_WH2T = 36864000;
static constexpr size_t OFF_XPRE = 38961152;     // 16.78MB (xpre1 then xpre2)
static constexpr size_t OFF_HSTA_HI = 55738368;
static constexpr size_t OFF_HSTA_LO = 57868288;
static constexpr size_t OFF_HSTB_HI = 59998208;
static constexpr size_t OFF_HSTB_LO = 62128128;
static constexpr size_t OFF_CBUF = 64258048;
static constexpr size_t OFF_BAR = 64323584;      // end 64,323,840

extern "C" void kernel_launch(void* const* d_in, const int* in_sizes, int n_in,
                              void* d_out, int out_size, void* d_ws, size_t ws_size,
                              hipStream_t stream) {
  (void)in_sizes; (void)n_in; (void)out_size; (void)ws_size;
  const int* x = (const int*)d_in[0];
  const float* enc = (const float*)d_in[1];
  const float* h0 = (const float*)d_in[2];
  const float* c0 = (const float*)d_in[3];
  const float* emb = (const float*)d_in[4];
  const float* W1 = (const float*)d_in[5];
  const float* b1 = (const float*)d_in[6];
  const float* W2 = (const float*)d_in[7];
  const float* b2 = (const float*)d_in[8];
  const float* Va = (const float*)d_in[9];
  const float* bV = (const float*)d_in[10];
  const float* Wx1 = (const float*)d_in[11];
  const float* Wh1 = (const float*)d_in[12];
  const float* bl1 = (const float*)d_in[13];
  const float* Wx2 = (const float*)d_in[14];
  const float* Wh2 = (const float*)d_in[15];
  const float* bl2 = (const float*)d_in[16];
  const float* Wfc = (const float*)d_in[17];
  const float* bfc = (const float*)d_in[18];
  float* out = (float*)d_out;
  char* ws = (char*)d_ws;

  u16* enc_hi = (u16*)(ws + OFF_ENC_HI);
  u16* enc_lo = (u16*)(ws + OFF_ENC_LO);
  u16* W1t_hi = (u16*)(ws + OFF_W1T_HI);
  u16* W1t_lo = (u16*)(ws + OFF_W1T_LO);
  u16* xcat_hi = (u16*)(ws + OFF_XCAT_HI);
  u16* xcat_lo = (u16*)(ws + OFF_XCAT_LO);
  u16* Wx1t_hi = (u16*)(ws + OFF_WX1T_HI);
  u16* Wx1t_lo = (u16*)(ws + OFF_WX1T_LO);
  u16* Wx2t_hi = (u16*)(ws + OFF_WX2T_HI);
  u16* Wx2t_lo = (u16*)(ws + OFF_WX2T_LO);
  float* t1 = (float*)(ws + OFF_T1);
  u16* Wfct = (u16*)(ws + OFF_WFCT);
  float* hw2 = (float*)(ws + OFF_HW2);
  float* score = (float*)(ws + OFF_SCORE);
  float* ctx = (float*)(ws + OFF_CTX);
  float* bl1p = (float*)(ws + OFF_BL1P);
  float* bl2p = (float*)(ws + OFF_BL2P);
  u16* Wh1t = (u16*)(ws + OFF_WH1T);
  u16* Wh2t = (u16*)(ws + OFF_WH2T);
  float* xpre = (float*)(ws + OFF_XPRE);
  u16* hstA_hi = (u16*)(ws + OFF_HSTA_HI);
  u16* hstA_lo = (u16*)(ws + OFF_HSTA_LO);
  u16* hstB_hi = (u16*)(ws + OFF_HSTB_HI);
  u16* hstB_lo = (u16*)(ws + OFF_HSTB_LO);
  float* cbuf = (float*)(ws + OFF_CBUF);
  u32* cntA = (u32*)(ws + OFF_BAR);
  u32* cntB = (u32*)(ws + OFF_BAR + 128);

  float* out_hT = out + 65536000;
  float* out_cT = out + 65552384;
  float* out_pesos = out + 65568768;

  hipMemsetAsync(ws + OFF_BAR, 0, 256, stream);

  // ---- attention (fp32-grade via 3-pass split bf16) ----
  k_split<<<8192, 256, 0, stream>>>(enc, enc_hi, enc_lo, 4096 * 512);
  k_transconv<false, true><<<dim3(16, 16), 256, 0, stream>>>(W1, W1t_hi, W1t_lo, 512, 512);
  k_hw2<<<32, 256, 0, stream>>>(h0, W2, b1, b2, hw2);
  gemm_bt<3, 0><<<32 * 4, 256, 0, stream>>>(enc_hi, enc_lo, W1t_hi, W1t_lo, t1, hw2, 4096, 512, 512);
  k_score<<<1024, 256, 0, stream>>>(t1, Va, bV, score);
  k_softmax_ctx<<<32, 128, 0, stream>>>(score, enc, out_pesos, ctx);

  // ---- weight conversions (transposed, unit-major gate permute) ----
  k_embcat<<<2048, 256, 0, stream>>>(x, emb, ctx, xcat_hi, xcat_lo);
  k_transconv<true, true><<<dim3(64, 24), 256, 0, stream>>>(Wx1, Wx1t_hi, Wx1t_lo, 768, 2048);
  k_transconv<true, false><<<dim3(64, 16), 256, 0, stream>>>(Wh1, Wh1t, nullptr, 512, 2048);
  k_transconv<true, true><<<dim3(64, 16), 256, 0, stream>>>(Wx2, Wx2t_hi, Wx2t_lo, 512, 2048);
  k_transconv<true, false><<<dim3(64, 16), 256, 0, stream>>>(Wh2, Wh2t, nullptr, 512, 2048);
  k_permbias<<<8, 256, 0, stream>>>(bl1, bl1p);
  k_permbias<<<8, 256, 0, stream>>>(bl2, bl2p);

  // ---- layer 1: xpre1 = xcat@Wx1 + bl1 ; scan ----
  gemm_bt<3, 1><<<16 * 16, 256, 0, stream>>>(xcat_hi, xcat_lo, Wx1t_hi, Wx1t_lo, xpre, bl1p, 2048, 2048, 768);
  k_initstate<<<64, 256, 0, stream>>>(h0, c0, hstA_hi, hstA_lo, cbuf);
  {
    ScanArgs s1{xpre, Wh1t, hstA_hi, hstA_lo, cbuf, nullptr, nullptr, cntA, 64, 0};
    void* kp[] = {&s1};
    hipLaunchCooperativeKernel((const void*)lstm_scan, dim3(64), dim3(128), kp, 0, stream);
  }

  // ---- layer 2 init: h2_0 = h1_T (c continues in cbuf) ----
  hipMemcpyAsync(hstB_hi, hstA_hi + (64 << 14), 32 * 512 * sizeof(u16), hipMemcpyDeviceToDevice, stream);
  hipMemcpyAsync(hstB_lo, hstA_lo + (64 << 14), 32 * 512 * sizeof(u16), hipMemcpyDeviceToDevice, stream);

  // ---- xpre2 = h1seq@Wx2 + bl2 (reuses xpre buffer) ----
  gemm_bt<3, 1><<<16 * 16, 256, 0, stream>>>(hstA_hi + 16384, hstA_lo + 16384, Wx2t_hi, Wx2t_lo,
                                             xpre, bl2p, 2048, 2048, 512);
  // Wfc^T convert into the (now dead) phase-1 region
  k_transconv<false, false><<<dim3(1000, 16), 256, 0, stream>>>(Wfc, Wfct, nullptr, 512, 32000);

  {
    ScanArgs s2{xpre, Wh2t, hstB_hi, hstB_lo, cbuf, out_hT, out_cT, cntB, 64, 1};
    void* kp[] = {&s2};
    hipLaunchCooperativeKernel((const void*)lstm_scan, dim3(64), dim3(128), kp, 0, stream);
  }

  // ---- projection: salidas = h2seq@Wfc + bfc (2-pass split-A) ----
  gemm_bt<2, 2><<<16 * 250, 256, 0, stream>>>(hstB_hi + 16384, hstB_lo + 16384, Wfct, Wfct,
                                              out, bfc, 2048, 32000, 512);
}

// Round 3
// 2295.240 us; speedup vs baseline: 1.3051x; 1.3051x over previous
//
#include <hip/hip_runtime.h>

typedef unsigned short u16;
typedef unsigned int u32;
typedef __attribute__((ext_vector_type(4))) float f32x4;
typedef __attribute__((ext_vector_type(8))) __bf16 bf16x8;

__device__ __forceinline__ u16 f2bf(float f) {
  u32 u = __builtin_bit_cast(u32, f);
  u += 0x7FFFu + ((u >> 16) & 1u);
  return (u16)(u >> 16);
}
__device__ __forceinline__ float bf2f(u16 h) {
  return __builtin_bit_cast(float, (u32)h << 16);
}

// ---------------------------------------------------------------------------
// Generic split: fp32 -> bf16 hi + bf16 lo (residual)
// ---------------------------------------------------------------------------
__global__ __launch_bounds__(256) void k_split(const float* __restrict__ in,
                                               u16* __restrict__ hi, u16* __restrict__ lo, int n) {
  int i = blockIdx.x * 256 + threadIdx.x;
  if (i >= n) return;
  float v = in[i];
  u16 h = f2bf(v);
  hi[i] = h;
  lo[i] = f2bf(v - bf2f(h));
}

// ---------------------------------------------------------------------------
// Transpose + convert (+ optional unit-major gate permute on out-rows):
// in: W fp32 [K][N] row-major  ->  out: bf16 [N][K] (B^T layout for gemm_bt)
// PERM: out row n' pulls input col (n'&3)*512 + (n'>>2)   (i,f,g,o -> unit-major)
// ---------------------------------------------------------------------------
template<bool PERM, bool SPLIT>
__global__ __launch_bounds__(256) void k_transconv(const float* __restrict__ W,
                                                   u16* __restrict__ Thi, u16* __restrict__ Tlo,
                                                   int K, int N) {
  __shared__ float tile[32][33];
  int n0 = blockIdx.x * 32, k0 = blockIdx.y * 32;
  int tx = threadIdx.x & 31, ty = threadIdx.x >> 5;
#pragma unroll
  for (int i = 0; i < 4; ++i) {
    int kk = ty + i * 8;
    int np = n0 + tx;
    int nin = PERM ? ((np & 3) * 512 + (np >> 2)) : np;
    tile[kk][tx] = W[(size_t)(k0 + kk) * N + nin];
  }
  __syncthreads();
#pragma unroll
  for (int i = 0; i < 4; ++i) {
    int rr = ty + i * 8;
    float v = tile[tx][rr];
    u16 h = f2bf(v);
    Thi[(size_t)(n0 + rr) * K + k0 + tx] = h;
    if (SPLIT) Tlo[(size_t)(n0 + rr) * K + k0 + tx] = f2bf(v - bf2f(h));
  }
}

// ---------------------------------------------------------------------------
// hw2[b][u] = estado_h[b]·W2[:,u] + b1[u] + b2[u]    (fp32, 32 blocks)
// ---------------------------------------------------------------------------
__global__ __launch_bounds__(256) void k_hw2(const float* __restrict__ h0, const float* __restrict__ W2,
                                             const float* __restrict__ b1, const float* __restrict__ b2,
                                             float* __restrict__ hw2) {
  int b = blockIdx.x;
  __shared__ float hs[512];
  for (int i = threadIdx.x; i < 512; i += 256) hs[i] = h0[b * 512 + i];
  __syncthreads();
  for (int u = threadIdx.x; u < 512; u += 256) {
    float acc = 0.f;
#pragma unroll 4
    for (int k = 0; k < 512; ++k) acc = fmaf(hs[k], W2[k * 512 + u], acc);
    hw2[b * 512 + u] = acc + b1[u] + b2[u];
  }
}

// ---------------------------------------------------------------------------
// score[r] = t1[r,:]·Va + bV   (t1 already tanh'ed), one wave per row
// ---------------------------------------------------------------------------
__global__ __launch_bounds__(256) void k_score(const float* __restrict__ t1, const float* __restrict__ Va,
                                               const float* __restrict__ bV, float* __restrict__ score) {
  int r = blockIdx.x * 4 + (threadIdx.x >> 6);
  int l = threadIdx.x & 63;
  const float* row = t1 + (size_t)r * 512;
  float acc = 0.f;
#pragma unroll
  for (int i = 0; i < 8; ++i) acc = fmaf(row[l + 64 * i], Va[l + 64 * i], acc);
#pragma unroll
  for (int off = 32; off >= 1; off >>= 1) acc += __shfl_down(acc, off, 64);
  if (l == 0) score[r] = acc + bV[0];
}

// ---------------------------------------------------------------------------
// softmax over S=128 + ctx[b] = sum_s pesos*enc ; writes pesos to d_out
// ---------------------------------------------------------------------------
__global__ __launch_bounds__(128) void k_softmax_ctx(const float* __restrict__ score,
                                                     const float* __restrict__ enc,
                                                     float* __restrict__ pesos, float* __restrict__ ctx) {
  int b = blockIdx.x, s = threadIdx.x;
  __shared__ float red[128], ps[128];
  float sc = score[(b << 7) + s];
  red[s] = sc;
  __syncthreads();
  for (int off = 64; off >= 1; off >>= 1) {
    if (s < off) red[s] = fmaxf(red[s], red[s + off]);
    __syncthreads();
  }
  float mx = red[0];
  __syncthreads();
  float e = expf(sc - mx);
  red[s] = e;
  __syncthreads();
  for (int off = 64; off >= 1; off >>= 1) {
    if (s < off) red[s] += red[s + off];
    __syncthreads();
  }
  float p = e / red[0];
  pesos[(b << 7) + s] = p;
  ps[s] = p;
  __syncthreads();
  for (int e0 = s; e0 < 512; e0 += 128) {
    float acc = 0.f;
    for (int si = 0; si < 128; ++si)
      acc = fmaf(ps[si], enc[((size_t)(b << 7) + si) * 512 + e0], acc);
    ctx[(b << 9) + e0] = acc;
  }
}

// ---------------------------------------------------------------------------
// xcat[row=t*32+b][0:256]=emb[x[b,t]], [256:768]=ctx[b]  -> bf16 hi/lo splits
// ---------------------------------------------------------------------------
__global__ __launch_bounds__(256) void k_embcat(const int* __restrict__ x, const float* __restrict__ emb,
                                                const float* __restrict__ ctx,
                                                u16* __restrict__ xhi, u16* __restrict__ xlo) {
  int r = blockIdx.x;
  int t = r >> 5, b = r & 31;
  int tok = x[b * 64 + t];
  for (int c = threadIdx.x; c < 768; c += 256) {
    float v = (c < 256) ? emb[(size_t)tok * 256 + c] : ctx[(b << 9) + (c - 256)];
    u16 h = f2bf(v);
    xhi[(size_t)r * 768 + c] = h;
    xlo[(size_t)r * 768 + c] = f2bf(v - bf2f(h));
  }
}

// bias permute: blp[c'] = bl[(c'&3)*512 + (c'>>2)]
__global__ __launch_bounds__(256) void k_permbias(const float* __restrict__ bl, float* __restrict__ blp) {
  int i = blockIdx.x * 256 + threadIdx.x;
  if (i < 2048) blp[i] = bl[(i & 3) * 512 + (i >> 2)];
}

// init: hstate rows 0 <- split(estado_h); c_buf <- estado_c
__global__ __launch_bounds__(256) void k_initstate(const float* __restrict__ h0, const float* __restrict__ c0,
                                                   u16* __restrict__ hhi, u16* __restrict__ hlo,
                                                   float* __restrict__ cbuf) {
  int i = blockIdx.x * 256 + threadIdx.x;  // 16384
  float v = h0[i];
  u16 h = f2bf(v);
  hhi[i] = h;
  hlo[i] = f2bf(v - bf2f(h));
  cbuf[i] = c0[i];
}

// ---------------------------------------------------------------------------
// MFMA GEMM, C[M,N] = A[M,K] @ B[K,N], B passed TRANSPOSED bf16 [N][K].
// A passed as bf16 splits (hi,lo). NPASS=2: Ahi*Bhi+Alo*Bhi ; NPASS=3: +Ahi*Blo.
// 128x128 tile, BK=32, 256 threads (4 waves, 2x2 of 64x64).
// EPI 0: C = tanh(acc + aux[(row>>7)*N + col])      (attention t1)
// EPI 1: C = acc + aux[col]                          (xpre + bias)
// EPI 2: C[(b*64+t)*N+col] = acc + aux[col], b=row&31,t=row>>5   (projection)
// ---------------------------------------------------------------------------
template<int NPASS, int EPI>
__global__ __launch_bounds__(256) void gemm_bt(const u16* __restrict__ Ahi, const u16* __restrict__ Alo,
                                               const u16* __restrict__ Bhi, const u16* __restrict__ Blo,
                                               float* __restrict__ C, const float* __restrict__ aux,
                                               int M, int N, int K) {
  __shared__ u16 sAhi[128][32], sAlo[128][32], sBhi[128][32], sBlo[128][32];
  const int NT = N >> 7;
  const int bm = blockIdx.x / NT, bn = blockIdx.x % NT;
  const int rowA0 = bm << 7, rowB0 = bn << 7;
  const int tid = threadIdx.x;
  const int l = tid & 63;
  const int w = tid >> 6, wr = w >> 1, wc = w & 1;
  const int lr = l & 15, kc = l >> 4;
  const int swz = (kc ^ ((lr >> 1) & 3)) << 3;
  f32x4 acc[4][4] = {};
  for (int ks = 0; ks < K; ks += 32) {
#pragma unroll
    for (int c = 0; c < 2; ++c) {
      int q = tid + (c << 8);
      int row = q >> 2, cc = q & 3;
      int slot = (cc ^ ((row >> 1) & 3)) << 3;
      size_t ga = (size_t)(rowA0 + row) * K + ks + (cc << 3);
      size_t gb = (size_t)(rowB0 + row) * K + ks + (cc << 3);
      *(uint4*)&sAhi[row][slot] = *(const uint4*)(Ahi + ga);
      *(uint4*)&sAlo[row][slot] = *(const uint4*)(Alo + ga);
      *(uint4*)&sBhi[row][slot] = *(const uint4*)(Bhi + gb);
      if (NPASS == 3) *(uint4*)&sBlo[row][slot] = *(const uint4*)(Blo + gb);
    }
    __syncthreads();
    bf16x8 ah[4], al[4], bh[4], bl2[4];
#pragma unroll
    for (int m = 0; m < 4; ++m) {
      ah[m] = *(const bf16x8*)&sAhi[(wr << 6) + (m << 4) + lr][swz];
      al[m] = *(const bf16x8*)&sAlo[(wr << 6) + (m << 4) + lr][swz];
      bh[m] = *(const bf16x8*)&sBhi[(wc << 6) + (m << 4) + lr][swz];
      if (NPASS == 3) bl2[m] = *(const bf16x8*)&sBlo[(wc << 6) + (m << 4) + lr][swz];
    }
#pragma unroll
    for (int m = 0; m < 4; ++m)
#pragma unroll
      for (int n = 0; n < 4; ++n) {
        acc[m][n] = __builtin_amdgcn_mfma_f32_16x16x32_bf16(ah[m], bh[n], acc[m][n], 0, 0, 0);
        acc[m][n] = __builtin_amdgcn_mfma_f32_16x16x32_bf16(al[m], bh[n], acc[m][n], 0, 0, 0);
        if (NPASS == 3)
          acc[m][n] = __builtin_amdgcn_mfma_f32_16x16x32_bf16(ah[m], bl2[n], acc[m][n], 0, 0, 0);
      }
    __syncthreads();
  }
#pragma unroll
  for (int m = 0; m < 4; ++m)
#pragma unroll
    for (int n = 0; n < 4; ++n)
#pragma unroll
      for (int r = 0; r < 4; ++r) {
        int rr = rowA0 + (wr << 6) + (m << 4) + (kc << 2) + r;
        int col = rowB0 + (wc << 6) + (n << 4) + lr;
        float v = acc[m][n][r];
        if (EPI == 0) {
          C[(size_t)rr * N + col] = tanhf(v + aux[(rr >> 7) * N + col]);
        } else if (EPI == 1) {
          C[(size_t)rr * N + col] = v + aux[col];
        } else {
          int b = rr & 31, t = rr >> 5;
          C[(size_t)(b * 64 + t) * N + col] = v + aux[col];
        }
      }
}

// ---------------------------------------------------------------------------
// LSTM scan v2. 32 blocks x 256 threads (4 waves). Block j owns 64 permuted
// z-cols (units 16j..16j+16); wave w owns cols 16w..16w+16 of those.
// Wh^T slice resident in VGPRs (64/thread, launch_bounds(256,1) so it stays).
// h state: write-once-per-step global regions; producers store via RELAXED
// agent-scope u32 atomics (bypass L2 -> coherent point), consumers use normal
// cached loads (region never cached before its write => never stale).
// Barrier: relaxed fetch_add + relaxed spin + ONE acquire after exit
// (single buffer_inv per step instead of one per poll).
// c state entirely in registers (block-private across steps).
// ---------------------------------------------------------------------------
struct ScanArgs {
  const float* xpre;   // [T*32][2048] fp32, unit-major cols, includes bias
  const u16* Wht;      // [2048][512] bf16 (B^T, permuted)
  u16* hhi;            // [(T+1)*32][512]
  u16* hlo;
  float* cbuf;         // [32][512] fp32 (in: c0; out: cT)
  float* hT_out;       // d_out slices (layer 2) or nullptr
  float* cT_out;
  u32* cnt;            // barrier counter (zeroed per launch)
  int T;
  int write_hc;
};

__global__ __launch_bounds__(256, 1) void lstm_scan(ScanArgs a) {
  const int j = blockIdx.x;              // 0..31
  const int tid = threadIdx.x;           // 0..255
  const int l = tid & 63, w = tid >> 6;  // lane, wave 0..3
  const int lr = l & 15, kc = l >> 4;    // fragment coords
  const int b_g = tid & 31, up = tid >> 5;  // gate phase: batch, unit-pair 0..7
  __shared__ float zs2[64][33];          // [col][batch]
  // Wh^T fragments resident in VGPRs (wave w: cols 64j+16w .. +16)
  bf16x8 breg[16];
  {
    const u16* bp = a.Wht + (size_t)(64 * j + 16 * w + lr) * 512 + (kc << 3);
#pragma unroll
    for (int q = 0; q < 16; ++q) breg[q] = *(const bf16x8*)(bp + (q << 5));
  }
  // c state in registers: thread owns (b_g, units 16j+2up, 16j+2up+1)
  const int ug0 = (j << 4) + (up << 1);
  float c0r = a.cbuf[(b_g << 9) + ug0];
  float c1r = a.cbuf[(b_g << 9) + ug0 + 1];
  u32* hhi32 = (u32*)a.hhi;
  u32* hlo32 = (u32*)a.hlo;
  for (int t = 0; t < a.T; ++t) {
    f32x4 acc0a = {0.f, 0.f, 0.f, 0.f}, acc0b = {0.f, 0.f, 0.f, 0.f};
    f32x4 acc1a = {0.f, 0.f, 0.f, 0.f}, acc1b = {0.f, 0.f, 0.f, 0.f};
    const u16* hh = a.hhi + ((size_t)t << 14) + ((size_t)lr << 9) + (kc << 3);
    const u16* hl = a.hlo + ((size_t)t << 14) + ((size_t)lr << 9) + (kc << 3);
#pragma unroll
    for (int q = 0; q < 16; ++q) {
      bf16x8 a0 = *(const bf16x8*)(hh + (q << 5));
      bf16x8 a1 = *(const bf16x8*)(hh + 8192 + (q << 5));
      bf16x8 l0 = *(const bf16x8*)(hl + (q << 5));
      bf16x8 l1 = *(const bf16x8*)(hl + 8192 + (q << 5));
      if (q < 8) {
        acc0a = __builtin_amdgcn_mfma_f32_16x16x32_bf16(a0, breg[q], acc0a, 0, 0, 0);
        acc0a = __builtin_amdgcn_mfma_f32_16x16x32_bf16(l0, breg[q], acc0a, 0, 0, 0);
        acc1a = __builtin_amdgcn_mfma_f32_16x16x32_bf16(a1, breg[q], acc1a, 0, 0, 0);
        acc1a = __builtin_amdgcn_mfma_f32_16x16x32_bf16(l1, breg[q], acc1a, 0, 0, 0);
      } else {
        acc0b = __builtin_amdgcn_mfma_f32_16x16x32_bf16(a0, breg[q], acc0b, 0, 0, 0);
        acc0b = __builtin_amdgcn_mfma_f32_16x16x32_bf16(l0, breg[q], acc0b, 0, 0, 0);
        acc1b = __builtin_amdgcn_mfma_f32_16x16x32_bf16(a1, breg[q], acc1b, 0, 0, 0);
        acc1b = __builtin_amdgcn_mfma_f32_16x16x32_bf16(l1, breg[q], acc1b, 0, 0, 0);
      }
    }
    f32x4 z0 = acc0a + acc0b, z1 = acc1a + acc1b;
#pragma unroll
    for (int r = 0; r < 4; ++r) {
      zs2[(w << 4) + lr][(kc << 2) + r] = z0[r];        // batches 0-15
      zs2[(w << 4) + lr][16 + (kc << 2) + r] = z1[r];   // batches 16-31
    }
    __syncthreads();
    // ---- gate phase: 2 units per thread ----
    const float* xp = a.xpre + (size_t)((t << 5) + b_g) * 2048 + (j << 6) + (up << 3);
    float4 zx0 = *(const float4*)xp;
    float4 zx1 = *(const float4*)(xp + 4);
    int c = up << 3;
    float zi0 = zs2[c + 0][b_g] + zx0.x;
    float zf0 = zs2[c + 1][b_g] + zx0.y;
    float zg0 = zs2[c + 2][b_g] + zx0.z;
    float zo0 = zs2[c + 3][b_g] + zx0.w;
    float zi1 = zs2[c + 4][b_g] + zx1.x;
    float zf1 = zs2[c + 5][b_g] + zx1.y;
    float zg1 = zs2[c + 6][b_g] + zx1.z;
    float zo1 = zs2[c + 7][b_g] + zx1.w;
    float si0 = 1.f / (1.f + expf(-zi0)), sf0 = 1.f / (1.f + expf(-zf0));
    float so0 = 1.f / (1.f + expf(-zo0));
    float si1 = 1.f / (1.f + expf(-zi1)), sf1 = 1.f / (1.f + expf(-zf1));
    float so1 = 1.f / (1.f + expf(-zo1));
    float cn0 = sf0 * c0r + si0 * tanhf(zg0);
    float cn1 = sf1 * c1r + si1 * tanhf(zg1);
    float hn0 = so0 * tanhf(cn0);
    float hn1 = so1 * tanhf(cn1);
    c0r = cn0;
    c1r = cn1;
    u16 h0b = f2bf(hn0), h1b = f2bf(hn1);
    u16 l0b = f2bf(hn0 - bf2f(h0b)), l1b = f2bf(hn1 - bf2f(h1b));
    size_t widx = ((size_t)(t + 1) << 13) + ((size_t)b_g << 8) + (j << 3) + up;
    __hip_atomic_store(hhi32 + widx, (u32)h0b | ((u32)h1b << 16),
                       __ATOMIC_RELAXED, __HIP_MEMORY_SCOPE_AGENT);
    __hip_atomic_store(hlo32 + widx, (u32)l0b | ((u32)l1b << 16),
                       __ATOMIC_RELAXED, __HIP_MEMORY_SCOPE_AGENT);
    if (t == a.T - 1) {
      a.cbuf[(b_g << 9) + ug0] = cn0;
      a.cbuf[(b_g << 9) + ug0 + 1] = cn1;
      if (a.write_hc) {
        a.hT_out[(b_g << 9) + ug0] = hn0;
        a.hT_out[(b_g << 9) + ug0 + 1] = hn1;
        a.cT_out[(b_g << 9) + ug0] = cn0;
        a.cT_out[(b_g << 9) + ug0 + 1] = cn1;
      }
    } else {
      asm volatile("s_waitcnt vmcnt(0)" ::: "memory");
      __syncthreads();  // all stores in block drained; also protects zs2 reuse
      if (tid == 0) {
        __hip_atomic_fetch_add(a.cnt, 1u, __ATOMIC_RELAXED, __HIP_MEMORY_SCOPE_AGENT);
        u32 tgt = (u32)(32 * (t + 1));
        while (__hip_atomic_load(a.cnt, __ATOMIC_RELAXED, __HIP_MEMORY_SCOPE_AGENT) < tgt)
          __builtin_amdgcn_s_sleep(1);
        (void)__hip_atomic_load(a.cnt, __ATOMIC_ACQUIRE, __HIP_MEMORY_SCOPE_AGENT);
      }
      __syncthreads();
    }
  }
}

// ---------------------------------------------------------------------------
// Workspace layout (bytes); ~64.4 MB total. Phase-1 region reused for Wfc^T.
// ---------------------------------------------------------------------------
static constexpr size_t OFF_ENC_HI = 0;
static constexpr size_t OFF_ENC_LO = 4194304;
static constexpr size_t OFF_W1T_HI = 8388608;
static constexpr size_t OFF_W1T_LO = 8912896;
static constexpr size_t OFF_XCAT_HI = 9437184;
static constexpr size_t OFF_XCAT_LO = 12582912;
static constexpr size_t OFF_WX1T_HI = 15728640;
static constexpr size_t OFF_WX1T_LO = 18874368;
static constexpr size_t OFF_WX2T_HI = 22020096;
static constexpr size_t OFF_WX2T_LO = 24117248;
static constexpr size_t OFF_T1 = 26214400;       // 8.39MB, ends 34,603,008
static constexpr size_t OFF_WFCT = 0;            // 32.77MB alias, after deps dead
static constexpr size_t OFF_HW2 = 34603008;
static constexpr size_t OFF_SCORE = 34668544;
static constexpr size_t OFF_CTX = 34684928;
static constexpr size_t OFF_BL1P = 34750464;
static constexpr size_t OFF_BL2P = 34758656;
static constexpr size_t OFF_WH1T = 34766848;
static constexpr size_t OFF_WH2T = 36864000;
static constexpr size_t OFF_XPRE = 38961152;     // 16.78MB (xpre1 then xpre2)
static constexpr size_t OFF_HSTA_HI = 55738368;
static constexpr size_t OFF_HSTA_LO = 57868288;
static constexpr size_t OFF_HSTB_HI = 59998208;
static constexpr size_t OFF_HSTB_LO = 62128128;
static constexpr size_t OFF_CBUF = 64258048;
static constexpr size_t OFF_BAR = 64323584;      // end 64,323,840

extern "C" void kernel_launch(void* const* d_in, const int* in_sizes, int n_in,
                              void* d_out, int out_size, void* d_ws, size_t ws_size,
                              hipStream_t stream) {
  (void)in_sizes; (void)n_in; (void)out_size; (void)ws_size;
  const int* x = (const int*)d_in[0];
  const float* enc = (const float*)d_in[1];
  const float* h0 = (const float*)d_in[2];
  const float* c0 = (const float*)d_in[3];
  const float* emb = (const float*)d_in[4];
  const float* W1 = (const float*)d_in[5];
  const float* b1 = (const float*)d_in[6];
  const float* W2 = (const float*)d_in[7];
  const float* b2 = (const float*)d_in[8];
  const float* Va = (const float*)d_in[9];
  const float* bV = (const float*)d_in[10];
  const float* Wx1 = (const float*)d_in[11];
  const float* Wh1 = (const float*)d_in[12];
  const float* bl1 = (const float*)d_in[13];
  const float* Wx2 = (const float*)d_in[14];
  const float* Wh2 = (const float*)d_in[15];
  const float* bl2 = (const float*)d_in[16];
  const float* Wfc = (const float*)d_in[17];
  const float* bfc = (const float*)d_in[18];
  float* out = (float*)d_out;
  char* ws = (char*)d_ws;

  u16* enc_hi = (u16*)(ws + OFF_ENC_HI);
  u16* enc_lo = (u16*)(ws + OFF_ENC_LO);
  u16* W1t_hi = (u16*)(ws + OFF_W1T_HI);
  u16* W1t_lo = (u16*)(ws + OFF_W1T_LO);
  u16* xcat_hi = (u16*)(ws + OFF_XCAT_HI);
  u16* xcat_lo = (u16*)(ws + OFF_XCAT_LO);
  u16* Wx1t_hi = (u16*)(ws + OFF_WX1T_HI);
  u16* Wx1t_lo = (u16*)(ws + OFF_WX1T_LO);
  u16* Wx2t_hi = (u16*)(ws + OFF_WX2T_HI);
  u16* Wx2t_lo = (u16*)(ws + OFF_WX2T_LO);
  float* t1 = (float*)(ws + OFF_T1);
  u16* Wfct = (u16*)(ws + OFF_WFCT);
  float* hw2 = (float*)(ws + OFF_HW2);
  float* score = (float*)(ws + OFF_SCORE);
  float* ctx = (float*)(ws + OFF_CTX);
  float* bl1p = (float*)(ws + OFF_BL1P);
  float* bl2p = (float*)(ws + OFF_BL2P);
  u16* Wh1t = (u16*)(ws + OFF_WH1T);
  u16* Wh2t = (u16*)(ws + OFF_WH2T);
  float* xpre = (float*)(ws + OFF_XPRE);
  u16* hstA_hi = (u16*)(ws + OFF_HSTA_HI);
  u16* hstA_lo = (u16*)(ws + OFF_HSTA_LO);
  u16* hstB_hi = (u16*)(ws + OFF_HSTB_HI);
  u16* hstB_lo = (u16*)(ws + OFF_HSTB_LO);
  float* cbuf = (float*)(ws + OFF_CBUF);
  u32* cntA = (u32*)(ws + OFF_BAR);
  u32* cntB = (u32*)(ws + OFF_BAR + 128);

  float* out_hT = out + 65536000;
  float* out_cT = out + 65552384;
  float* out_pesos = out + 65568768;

  hipMemsetAsync(ws + OFF_BAR, 0, 256, stream);

  // ---- attention (fp32-grade via 3-pass split bf16) ----
  k_split<<<8192, 256, 0, stream>>>(enc, enc_hi, enc_lo, 4096 * 512);
  k_transconv<false, true><<<dim3(16, 16), 256, 0, stream>>>(W1, W1t_hi, W1t_lo, 512, 512);
  k_hw2<<<32, 256, 0, stream>>>(h0, W2, b1, b2, hw2);
  gemm_bt<3, 0><<<32 * 4, 256, 0, stream>>>(enc_hi, enc_lo, W1t_hi, W1t_lo, t1, hw2, 4096, 512, 512);
  k_score<<<1024, 256, 0, stream>>>(t1, Va, bV, score);
  k_softmax_ctx<<<32, 128, 0, stream>>>(score, enc, out_pesos, ctx);

  // ---- weight conversions (transposed, unit-major gate permute) ----
  k_embcat<<<2048, 256, 0, stream>>>(x, emb, ctx, xcat_hi, xcat_lo);
  k_transconv<true, true><<<dim3(64, 24), 256, 0, stream>>>(Wx1, Wx1t_hi, Wx1t_lo, 768, 2048);
  k_transconv<true, false><<<dim3(64, 16), 256, 0, stream>>>(Wh1, Wh1t, nullptr, 512, 2048);
  k_transconv<true, true><<<dim3(64, 16), 256, 0, stream>>>(Wx2, Wx2t_hi, Wx2t_lo, 512, 2048);
  k_transconv<true, false><<<dim3(64, 16), 256, 0, stream>>>(Wh2, Wh2t, nullptr, 512, 2048);
  k_permbias<<<8, 256, 0, stream>>>(bl1, bl1p);
  k_permbias<<<8, 256, 0, stream>>>(bl2, bl2p);

  // ---- layer 1: xpre1 = xcat@Wx1 + bl1 ; scan ----
  gemm_bt<3, 1><<<16 * 16, 256, 0, stream>>>(xcat_hi, xcat_lo, Wx1t_hi, Wx1t_lo, xpre, bl1p, 2048, 2048, 768);
  k_initstate<<<64, 256, 0, stream>>>(h0, c0, hstA_hi, hstA_lo, cbuf);
  {
    ScanArgs s1{xpre, Wh1t, hstA_hi, hstA_lo, cbuf, nullptr, nullptr, cntA, 64, 0};
    void* kp[] = {&s1};
    hipLaunchCooperativeKernel((const void*)lstm_scan, dim3(32), dim3(256), kp, 0, stream);
  }

  // ---- layer 2 init: h2_0 = h1_T (c continues via cbuf) ----
  hipMemcpyAsync(hstB_hi, hstA_hi + (64 << 14), 32 * 512 * sizeof(u16), hipMemcpyDeviceToDevice, stream);
  hipMemcpyAsync(hstB_lo, hstA_lo + (64 << 14), 32 * 512 * sizeof(u16), hipMemcpyDeviceToDevice, stream);

  // ---- xpre2 = h1seq@Wx2 + bl2 (reuses xpre buffer) ----
  gemm_bt<3, 1><<<16 * 16, 256, 0, stream>>>(hstA_hi + 16384, hstA_lo + 16384, Wx2t_hi, Wx2t_lo,
                                             xpre, bl2p, 2048, 2048, 512);
  // Wfc^T convert into the (now dead) phase-1 region
  k_transconv<false, false><<<dim3(1000, 16), 256, 0, stream>>>(Wfc, Wfct, nullptr, 512, 32000);

  {
    ScanArgs s2{xpre, Wh2t, hstB_hi, hstB_lo, cbuf, out_hT, out_cT, cntB, 64, 1};
    void* kp[] = {&s2};
    hipLaunchCooperativeKernel((const void*)lstm_scan, dim3(32), dim3(256), kp, 0, stream);
  }

  // ---- projection: salidas = h2seq@Wfc + bfc (2-pass split-A) ----
  gemm_bt<2, 2><<<16 * 250, 256, 0, stream>>>(hstB_hi + 16384, hstB_lo + 16384, Wfct, Wfct,
                                              out, bfc, 2048, 32000, 512);
}